// Round 1
// 248.113 us; speedup vs baseline: 1.0239x; 1.0239x over previous
//
#include <hip/hip_runtime.h>
#include <hip/hip_fp16.h>

#define N_NODES 50000
#define N_EDGES 1250000
#define HDIM    64
#define NGRAPH  64
#define NPART   400                        // partitions for CSR build
#define PSIZE   125                        // nodes per partition (400*125 = 50000 exact)
#define CAP     4096                       // bucket capacity per partition (mean 3125, sigma 56 -> +17 sigma)

struct alignas(8) h4 { __half2 a, b; };    // 4 fp16 features, one 8-byte load/store
struct alignas(16) h8 { __half2 a, b, c, d; };  // 8 fp16 features, one 16-byte LDS read

// fp16 dot2 with fp32 accumulate: v_dot2_f32_f16 if available, else unpack+fma
typedef _Float16 half2v __attribute__((ext_vector_type(2)));
#if __has_builtin(__builtin_amdgcn_fdot2)
__device__ inline float dot2acc(__half2 a, __half2 b, float c) {
    return __builtin_amdgcn_fdot2(__builtin_bit_cast(half2v, a),
                                  __builtin_bit_cast(half2v, b), c, false);
}
#else
__device__ inline float dot2acc(__half2 a, __half2 b, float c) {
    float2 fa = __half22float2(a), fb = __half22float2(b);
    return c + fa.x * fb.x + fa.y * fb.y;
}
#endif

// ---------------------------------------------------------------- bucket edges by partition
__global__ void bucket_kernel(const int* __restrict__ ei, int* __restrict__ pcount,
                              int* __restrict__ bucket) {
    __shared__ int hist[NPART];
    __shared__ int sbase[NPART];
    int tid = threadIdx.x;
    for (int i = tid; i < NPART; i += 256) hist[i] = 0;
    __syncthreads();
    int chunk = (N_EDGES + gridDim.x - 1) / gridDim.x;
    int beg = blockIdx.x * chunk;
    int end = min(beg + chunk, N_EDGES);
    for (int e = beg + tid; e < end; e += 256)
        atomicAdd(&hist[ei[N_EDGES + e] / PSIZE], 1);
    __syncthreads();
    for (int i = tid; i < NPART; i += 256) {
        sbase[i] = hist[i] ? atomicAdd(&pcount[i], hist[i]) : 0;
        hist[i] = 0;   // reuse as local offset
    }
    __syncthreads();
    for (int e = beg + tid; e < end; e += 256) {
        int dst = ei[N_EDGES + e];
        int src = ei[e];
        int p = dst / PSIZE;
        int l = atomicAdd(&hist[p], 1);
        bucket[p * CAP + sbase[p] + l] = (src << 8) | (dst - p * PSIZE);
    }
}

// ---------------------------------------------------------------- per-partition deg+scan+row ranges+dinv+fill (+graph node counts)
__global__ void csr_kernel(const int* __restrict__ pcount, const int* __restrict__ bucket,
                           const int* __restrict__ batch,
                           int* __restrict__ row_beg, int* __restrict__ row_end,
                           float* __restrict__ dinv, int* __restrict__ csr_src,
                           float* __restrict__ cnt) {
    __shared__ int hist[256];
    __shared__ int s[256];
    __shared__ int cur[128];
    __shared__ int ghist[64];
    int p = blockIdx.x;
    int tid = threadIdx.x;
    int base = p * CAP;
    int cntE = min(pcount[p], CAP);
    hist[tid] = 0;
    __syncthreads();
    for (int e = tid; e < cntE; e += 256)
        atomicAdd(&hist[bucket[base + e] & 0xFF], 1);
    __syncthreads();
    int v = (tid < PSIZE) ? hist[tid] : 0;
    s[tid] = v;
    __syncthreads();
    for (int off = 1; off < 256; off <<= 1) {
        int t = (tid >= off) ? s[tid - off] : 0;
        __syncthreads();
        s[tid] += t;
        __syncthreads();
    }
    if (tid < PSIZE) {
        int ex = s[tid] - v;
        int node = p * PSIZE + tid;
        row_beg[node] = base + ex;
        row_end[node] = base + ex + v;
        dinv[node] = rsqrtf((float)v + 1.0f);   // +1 self-loop
        cur[tid] = ex;
    }
    __syncthreads();
    for (int e = tid; e < cntE; e += 256) {
        int pk = bucket[base + e];
        int l = atomicAdd(&cur[pk & 0xFF], 1);
        csr_src[base + l] = pk >> 8;
    }
    // per-graph node counts (batch sorted: each partition touches only a few graphs)
    if (tid < 64) ghist[tid] = 0;
    __syncthreads();
    if (tid < PSIZE) atomicAdd(&ghist[batch[p * PSIZE + tid]], 1);
    __syncthreads();
    if (tid < 64 && ghist[tid]) atomicAdd(&cnt[tid], (float)ghist[tid]);
}

// ---------------------------------------------------------------- GEMM 64x64 -> fp16, row-scaled by dinv (layer 0 only, fp32 input)
__device__ inline __half2 stage2(const float* p, int i) {
    float2 v = ((const float2*)p)[i];
    return __floats2half2_rn(v.x, v.y);
}
__device__ inline __half2 stage2(const __half* p, int i) {
    return ((const __half2*)p)[i];
}

template <typename T>
__global__ void gemm64_kernel(const T* __restrict__ h, const float* __restrict__ W,
                              const float* __restrict__ dinv, __half* __restrict__ out) {
    __shared__ alignas(16) __half2 hs2[256];   // 8 rows x 32 half2 (fp16 tile)
    int tid = threadIdx.x;
    int tx = tid & 63;       // output column (lane)
    int r0 = (tid >> 6) * 2; // this wave's two rows within the 8-row chunk
    __half2 wcol2[32];       // W[:, tx] as fp16 pairs
#pragma unroll
    for (int k2 = 0; k2 < 32; ++k2)
        wcol2[k2] = __floats2half2_rn(W[(2 * k2) * 64 + tx], W[(2 * k2 + 1) * 64 + tx]);
    const int nchunks = N_NODES / 8;  // 6250, exact
    for (int grp = blockIdx.x; grp < nchunks; grp += gridDim.x) {
        __syncthreads();                       // protect hs2 from previous iter
        hs2[tid] = stage2(h + grp * 512, tid); // 8 rows of h -> fp16 LDS
        __syncthreads();
        float acc0 = 0.f, acc1 = 0.f;
        const h8* row0 = (const h8*)&hs2[r0 * 32];
        const h8* row1 = (const h8*)&hs2[(r0 + 1) * 32];
#pragma unroll
        for (int j = 0; j < 8; ++j) {
            h8 v0 = row0[j];
            h8 v1 = row1[j];
            acc0 = dot2acc(v0.a, wcol2[4 * j + 0], acc0);
            acc0 = dot2acc(v0.b, wcol2[4 * j + 1], acc0);
            acc0 = dot2acc(v0.c, wcol2[4 * j + 2], acc0);
            acc0 = dot2acc(v0.d, wcol2[4 * j + 3], acc0);
            acc1 = dot2acc(v1.a, wcol2[4 * j + 0], acc1);
            acc1 = dot2acc(v1.b, wcol2[4 * j + 1], acc1);
            acc1 = dot2acc(v1.c, wcol2[4 * j + 2], acc1);
            acc1 = dot2acc(v1.d, wcol2[4 * j + 3], acc1);
        }
        int nbase = grp * 8 + r0;
        out[nbase * 64 + tx]       = __float2half(acc0 * dinv[nbase]);
        out[(nbase + 1) * 64 + tx] = __float2half(acc1 * dinv[nbase + 1]);
    }
}

// ---------------------------------------------------------------- fused gather + relu + next-layer GEMM
// One 16-lane group per node (16 nodes/block). Gather phase identical to the old
// gather_g16; the post-relu h' row is staged to LDS (fp32) and the SAME block
// applies the next layer's 64x64 transform, writing dinv-scaled fp16 xws' directly.
// Removes: bufH round-trip, 1 kernel launch + gap per layer.
__global__ void fused_layer_kernel(const int* __restrict__ row_beg, const int* __restrict__ row_end,
                                   const int* __restrict__ csr_src, const float* __restrict__ dinv,
                                   const __half* __restrict__ xin, const float* __restrict__ b,
                                   const float* __restrict__ Wn, __half* __restrict__ xout) {
    __shared__ alignas(16) float hs[16][72];   // 72-float rows: 4 block-rows land on banks 0/8/16/24 -> conflict-free b128
    int tid = threadIdx.x;
    int nl  = tid >> 4;                        // local node 0..15
    int l4  = tid & 15;                        // feature quad
    int node = (blockIdx.x << 4) + nl;         // 3125*16 = 50000 exact, no tail
    int beg = row_beg[node];
    int end = row_end[node];
    float ax = 0.f, ay = 0.f, az = 0.f, aw = 0.f;
    int e = beg;
    for (; e + 3 < end; e += 4) {              // 4 independent row loads in flight
        int s0 = csr_src[e + 0];
        int s1 = csr_src[e + 1];
        int s2 = csr_src[e + 2];
        int s3 = csr_src[e + 3];
        h4 v0 = *(const h4*)(xin + s0 * 64 + 4 * l4);
        h4 v1 = *(const h4*)(xin + s1 * 64 + 4 * l4);
        h4 v2 = *(const h4*)(xin + s2 * 64 + 4 * l4);
        h4 v3 = *(const h4*)(xin + s3 * 64 + 4 * l4);
        float2 f0a = __half22float2(v0.a), f0b = __half22float2(v0.b);
        float2 f1a = __half22float2(v1.a), f1b = __half22float2(v1.b);
        float2 f2a = __half22float2(v2.a), f2b = __half22float2(v2.b);
        float2 f3a = __half22float2(v3.a), f3b = __half22float2(v3.b);
        ax += f0a.x + f1a.x + f2a.x + f3a.x;
        ay += f0a.y + f1a.y + f2a.y + f3a.y;
        az += f0b.x + f1b.x + f2b.x + f3b.x;
        aw += f0b.y + f1b.y + f2b.y + f3b.y;
    }
    for (; e < end; ++e) {
        int s = csr_src[e];
        h4 v = *(const h4*)(xin + s * 64 + 4 * l4);
        float2 fa = __half22float2(v.a), fb = __half22float2(v.b);
        ax += fa.x; ay += fa.y; az += fb.x; aw += fb.y;
    }
    float d = dinv[node];
    h4 sv = *(const h4*)(xin + node * 64 + 4 * l4);
    float2 sa = __half22float2(sv.a), sb = __half22float2(sv.b);
    const float4 bb = *(const float4*)(b + 4 * l4);
    float vx = fmaxf(d * (ax + sa.x) + bb.x, 0.f);   // relu (always on for fused layers)
    float vy = fmaxf(d * (ay + sa.y) + bb.y, 0.f);
    float vz = fmaxf(d * (az + sb.x) + bb.z, 0.f);
    float vw = fmaxf(d * (aw + sb.y) + bb.w, 0.f);
    *(float4*)&hs[nl][4 * l4] = make_float4(vx, vy, vz, vw);
    __syncthreads();
    // GEMM phase: thread (nl, j4=l4) computes xout[node][4*l4 .. 4*l4+3]
    float4 acc = make_float4(0.f, 0.f, 0.f, 0.f);
    const float* wp = Wn + 4 * l4;
#pragma unroll 4
    for (int k = 0; k < 16; ++k) {
        float4 hv = *(const float4*)&hs[nl][4 * k];            // LDS broadcast within group
        float4 w0 = *(const float4*)(wp + (4 * k + 0) * 64);   // L1-resident (16 KB total)
        float4 w1 = *(const float4*)(wp + (4 * k + 1) * 64);
        float4 w2 = *(const float4*)(wp + (4 * k + 2) * 64);
        float4 w3 = *(const float4*)(wp + (4 * k + 3) * 64);
        acc.x += hv.x * w0.x + hv.y * w1.x + hv.z * w2.x + hv.w * w3.x;
        acc.y += hv.x * w0.y + hv.y * w1.y + hv.z * w2.y + hv.w * w3.y;
        acc.z += hv.x * w0.z + hv.y * w1.z + hv.z * w2.z + hv.w * w3.z;
        acc.w += hv.x * w0.w + hv.y * w1.w + hv.z * w2.w + hv.w * w3.w;
    }
    h4 o;
    o.a = __float22half2_rn(make_float2(acc.x * d, acc.y * d));
    o.b = __float22half2_rn(make_float2(acc.z * d, acc.w * d));
    *(h4*)(xout + node * 64 + 4 * l4) = o;
}

// ---------------------------------------------------------------- fused final gather (no relu) + pooling
// batch is sorted, so ~98% of 16-node blocks are graph-uniform: reduce the block's
// 16 rows in LDS and emit 64 atomics; fall back to per-thread atomics at boundaries.
__global__ void gather_pool_kernel(const int* __restrict__ row_beg, const int* __restrict__ row_end,
                                   const int* __restrict__ csr_src, const float* __restrict__ dinv,
                                   const __half* __restrict__ xin, const float* __restrict__ b,
                                   const int* __restrict__ batch, float* __restrict__ pool) {
    __shared__ alignas(16) float hs[16][72];
    __shared__ int sg[16];
    __shared__ int allsame;
    int tid = threadIdx.x;
    int nl  = tid >> 4;
    int l4  = tid & 15;
    int node = (blockIdx.x << 4) + nl;
    int beg = row_beg[node];
    int end = row_end[node];
    float ax = 0.f, ay = 0.f, az = 0.f, aw = 0.f;
    int e = beg;
    for (; e + 3 < end; e += 4) {
        int s0 = csr_src[e + 0];
        int s1 = csr_src[e + 1];
        int s2 = csr_src[e + 2];
        int s3 = csr_src[e + 3];
        h4 v0 = *(const h4*)(xin + s0 * 64 + 4 * l4);
        h4 v1 = *(const h4*)(xin + s1 * 64 + 4 * l4);
        h4 v2 = *(const h4*)(xin + s2 * 64 + 4 * l4);
        h4 v3 = *(const h4*)(xin + s3 * 64 + 4 * l4);
        float2 f0a = __half22float2(v0.a), f0b = __half22float2(v0.b);
        float2 f1a = __half22float2(v1.a), f1b = __half22float2(v1.b);
        float2 f2a = __half22float2(v2.a), f2b = __half22float2(v2.b);
        float2 f3a = __half22float2(v3.a), f3b = __half22float2(v3.b);
        ax += f0a.x + f1a.x + f2a.x + f3a.x;
        ay += f0a.y + f1a.y + f2a.y + f3a.y;
        az += f0b.x + f1b.x + f2b.x + f3b.x;
        aw += f0b.y + f1b.y + f2b.y + f3b.y;
    }
    for (; e < end; ++e) {
        int s = csr_src[e];
        h4 v = *(const h4*)(xin + s * 64 + 4 * l4);
        float2 fa = __half22float2(v.a), fb = __half22float2(v.b);
        ax += fa.x; ay += fa.y; az += fb.x; aw += fb.y;
    }
    float d = dinv[node];
    h4 sv = *(const h4*)(xin + node * 64 + 4 * l4);
    float2 sa = __half22float2(sv.a), sb = __half22float2(sv.b);
    const float4 bb = *(const float4*)(b + 4 * l4);
    float vx = d * (ax + sa.x) + bb.x;   // no relu on last layer
    float vy = d * (ay + sa.y) + bb.y;
    float vz = d * (az + sb.x) + bb.z;
    float vw = d * (aw + sb.y) + bb.w;
    if (l4 == 0) sg[nl] = batch[node];
    if (tid == 0) allsame = 1;
    *(float4*)&hs[nl][4 * l4] = make_float4(vx, vy, vz, vw);
    __syncthreads();
    if (tid < 16 && sg[tid] != sg[0]) allsame = 0;   // benign race, all writes = 0
    __syncthreads();
    if (allsame) {
        if (tid < 64) {
            float s = 0.f;
#pragma unroll
            for (int n = 0; n < 16; ++n) s += hs[n][tid];
            atomicAdd(&pool[sg[0] * 64 + tid], s);
        }
    } else {
        int g = sg[nl];
        atomicAdd(&pool[g * 64 + 4 * l4 + 0], vx);
        atomicAdd(&pool[g * 64 + 4 * l4 + 1], vy);
        atomicAdd(&pool[g * 64 + 4 * l4 + 2], vz);
        atomicAdd(&pool[g * 64 + 4 * l4 + 3], vw);
    }
}

// ---------------------------------------------------------------- head
__global__ void head_kernel(const float* __restrict__ pool, const float* __restrict__ cnt,
                            const float* __restrict__ Wp, const float* __restrict__ bp,
                            float* __restrict__ out) {
    int g = blockIdx.x;
    int k = threadIdx.x;
    float v = pool[g * 64 + k] * Wp[k];
#pragma unroll
    for (int off = 32; off > 0; off >>= 1) v += __shfl_down(v, off);
    if (k == 0) out[g] = v / fmaxf(cnt[g], 1.0f) + bp[0];
}

extern "C" void kernel_launch(void* const* d_in, const int* in_sizes, int n_in,
                              void* d_out, int out_size, void* d_ws, size_t ws_size,
                              hipStream_t stream) {
    const float* x     = (const float*)d_in[0];
    const int*   ei    = (const int*)d_in[1];    // [2, E] flat: row0=src, row1=dst
    const int*   batch = (const int*)d_in[2];
    const float* W0 = (const float*)d_in[3];
    const float* b0 = (const float*)d_in[4];
    const float* W1 = (const float*)d_in[5];
    const float* b1 = (const float*)d_in[6];
    const float* W2 = (const float*)d_in[7];
    const float* b2 = (const float*)d_in[8];
    const float* Wp = (const float*)d_in[9];
    const float* bp = (const float*)d_in[10];
    float* out = (float*)d_out;

    __half* xws  = (__half*)d_ws;                      // N*64 fp16 (ping)
    __half* xwsB = xws + N_NODES * 64;                 // N*64 fp16 (pong)
    float* dinv    = (float*)(xwsB + N_NODES * 64);    // N
    int*   row_beg = (int*)(dinv + N_NODES);           // N
    int*   row_end = row_beg + N_NODES;                // N
    int*   csr_src = row_end + N_NODES;                // NPART*CAP
    int*   bucket  = csr_src + NPART * CAP;            // NPART*CAP
    int*   pcount  = bucket + NPART * CAP;             // NPART   (contiguous with pool+cnt)
    float* pool    = (float*)(pcount + NPART);         // 64*64
    float* cnt     = pool + 64 * 64;                   // 64

    // single fused zero-fill: pcount + pool + cnt are contiguous
    hipMemsetAsync(pcount, 0, (NPART + 64 * 64 + 64) * sizeof(int), stream);

    // ---- CSR build
    bucket_kernel<<<512, 256, 0, stream>>>(ei, pcount, bucket);
    csr_kernel<<<NPART, 256, 0, stream>>>(pcount, bucket, batch, row_beg, row_end, dinv,
                                          csr_src, cnt);

    // ---- layer 0 transform (fp32 input x)
    gemm64_kernel<float><<<1024, 256, 0, stream>>>(x, W0, dinv, xws);
    // ---- fused: layer-0 aggregate + relu + layer-1 transform
    fused_layer_kernel<<<N_NODES / 16, 256, 0, stream>>>(row_beg, row_end, csr_src, dinv,
                                                         xws, b0, W1, xwsB);
    // ---- fused: layer-1 aggregate + relu + layer-2 transform
    fused_layer_kernel<<<N_NODES / 16, 256, 0, stream>>>(row_beg, row_end, csr_src, dinv,
                                                         xwsB, b1, W2, xws);
    // ---- fused: layer-2 aggregate (no relu) + pooling
    gather_pool_kernel<<<N_NODES / 16, 256, 0, stream>>>(row_beg, row_end, csr_src, dinv,
                                                         xws, b2, batch, pool);
    head_kernel<<<64, 64, 0, stream>>>(pool, cnt, Wp, bp, out);
}

// Round 3
// 210.211 us; speedup vs baseline: 1.2085x; 1.1803x over previous
//
#include <hip/hip_runtime.h>
#include <hip/hip_fp16.h>

#define N_NODES 50000
#define N_EDGES 1250000
#define HDIM    64
#define NGRAPH  64
#define NPART   400                        // partitions for CSR build
#define PSIZE   125                        // nodes per partition (400*125 = 50000 exact)
#define CAP     4096                       // bucket capacity per partition (mean 3125, sigma 56 -> +17 sigma)
#define NB     32                          // nodes per block in fused kernels (8 lanes/node)
#define NBLK   ((N_NODES + NB - 1) / NB)   // 1563

struct alignas(8) h4 { __half2 a, b; };         // 4 fp16 features
struct alignas(16) h8 { __half2 a, b, c, d; };  // 8 fp16 features, one 16-byte load

// fp16 dot2 with fp32 accumulate
typedef _Float16 half2v __attribute__((ext_vector_type(2)));
#if __has_builtin(__builtin_amdgcn_fdot2)
__device__ inline float dot2acc(__half2 a, __half2 b, float c) {
    return __builtin_amdgcn_fdot2(__builtin_bit_cast(half2v, a),
                                  __builtin_bit_cast(half2v, b), c, false);
}
#else
__device__ inline float dot2acc(__half2 a, __half2 b, float c) {
    float2 fa = __half22float2(a), fb = __half22float2(b);
    return c + fa.x * fb.x + fa.y * fb.y;
}
#endif

// ---------------------------------------------------------------- bucket edges by partition (int4 edge reads)
__global__ void bucket_kernel(const int* __restrict__ ei, int* __restrict__ pcount,
                              int* __restrict__ bucket) {
    __shared__ int hist[NPART];
    __shared__ int sbase[NPART];
    int tid = threadIdx.x;
    for (int i = tid; i < NPART; i += 256) hist[i] = 0;
    __syncthreads();
    int gtid = blockIdx.x * 256 + tid;
    int gstr = gridDim.x * 256;
    // phase 1: count (E divisible by 4)
    for (int e4 = gtid * 4; e4 < N_EDGES; e4 += gstr * 4) {
        int4 d = *(const int4*)(ei + N_EDGES + e4);
        atomicAdd(&hist[d.x / PSIZE], 1);
        atomicAdd(&hist[d.y / PSIZE], 1);
        atomicAdd(&hist[d.z / PSIZE], 1);
        atomicAdd(&hist[d.w / PSIZE], 1);
    }
    __syncthreads();
    // phase 2: reserve ranges
    for (int i = tid; i < NPART; i += 256) {
        sbase[i] = hist[i] ? atomicAdd(&pcount[i], hist[i]) : 0;
        hist[i] = 0;   // reuse as local offset
    }
    __syncthreads();
    // phase 3: scatter packed edges
    for (int e4 = gtid * 4; e4 < N_EDGES; e4 += gstr * 4) {
        int4 d = *(const int4*)(ei + N_EDGES + e4);
        int4 s = *(const int4*)(ei + e4);
        int p0 = d.x / PSIZE; int l0 = atomicAdd(&hist[p0], 1);
        bucket[p0 * CAP + sbase[p0] + l0] = (s.x << 8) | (d.x - p0 * PSIZE);
        int p1 = d.y / PSIZE; int l1 = atomicAdd(&hist[p1], 1);
        bucket[p1 * CAP + sbase[p1] + l1] = (s.y << 8) | (d.y - p1 * PSIZE);
        int p2 = d.z / PSIZE; int l2 = atomicAdd(&hist[p2], 1);
        bucket[p2 * CAP + sbase[p2] + l2] = (s.z << 8) | (d.z - p2 * PSIZE);
        int p3 = d.w / PSIZE; int l3 = atomicAdd(&hist[p3], 1);
        bucket[p3 * CAP + sbase[p3] + l3] = (s.w << 8) | (d.w - p3 * PSIZE);
    }
}

// ---------------------------------------------------------------- per-partition deg+scan+rows+dinv+fill (+graph node counts)
__global__ void csr_kernel(const int* __restrict__ pcount, const int* __restrict__ bucket,
                           const int* __restrict__ batch,
                           int* __restrict__ row_beg, int* __restrict__ row_end,
                           float* __restrict__ dinv, int* __restrict__ csr_src,
                           float* __restrict__ cnt) {
    __shared__ int hist[256];
    __shared__ int s[256];
    __shared__ int cur[128];
    __shared__ int ghist[64];
    int p = blockIdx.x;
    int tid = threadIdx.x;
    int base = p * CAP;
    int cntE = min(pcount[p], CAP);
    hist[tid] = 0;
    __syncthreads();
    for (int e = tid; e < cntE; e += 256)
        atomicAdd(&hist[bucket[base + e] & 0xFF], 1);
    __syncthreads();
    int v = (tid < PSIZE) ? hist[tid] : 0;
    s[tid] = v;
    __syncthreads();
    for (int off = 1; off < 256; off <<= 1) {
        int t = (tid >= off) ? s[tid - off] : 0;
        __syncthreads();
        s[tid] += t;
        __syncthreads();
    }
    if (tid < PSIZE) {
        int ex = s[tid] - v;
        int node = p * PSIZE + tid;
        row_beg[node] = base + ex;
        row_end[node] = base + ex + v;
        dinv[node] = rsqrtf((float)v + 1.0f);   // +1 self-loop
        cur[tid] = ex;
    }
    __syncthreads();
    for (int e = tid; e < cntE; e += 256) {
        int pk = bucket[base + e];
        int l = atomicAdd(&cur[pk & 0xFF], 1);
        csr_src[base + l] = pk >> 8;
    }
    if (tid < 64) ghist[tid] = 0;
    __syncthreads();
    if (tid < PSIZE) atomicAdd(&ghist[batch[p * PSIZE + tid]], 1);
    __syncthreads();
    if (tid < 64 && ghist[tid]) atomicAdd(&cnt[tid], (float)ghist[tid]);
}

// ---------------------------------------------------------------- GEMM 64x64 -> fp16, row-scaled by dinv (layer 0, fp32 input)
__device__ inline __half2 stage2(const float* p, int i) {
    float2 v = ((const float2*)p)[i];
    return __floats2half2_rn(v.x, v.y);
}
__device__ inline __half2 stage2(const __half* p, int i) {
    return ((const __half2*)p)[i];
}

template <typename T>
__global__ void gemm64_kernel(const T* __restrict__ h, const float* __restrict__ W,
                              const float* __restrict__ dinv, __half* __restrict__ out) {
    __shared__ alignas(16) __half2 hs2[256];   // 8 rows x 32 half2
    int tid = threadIdx.x;
    int tx = tid & 63;
    int r0 = (tid >> 6) * 2;
    __half2 wcol2[32];
#pragma unroll
    for (int k2 = 0; k2 < 32; ++k2)
        wcol2[k2] = __floats2half2_rn(W[(2 * k2) * 64 + tx], W[(2 * k2 + 1) * 64 + tx]);
    const int nchunks = N_NODES / 8;  // 6250
    for (int grp = blockIdx.x; grp < nchunks; grp += gridDim.x) {
        __syncthreads();
        hs2[tid] = stage2(h + grp * 512, tid);
        __syncthreads();
        float acc0 = 0.f, acc1 = 0.f;
        const h8* row0 = (const h8*)&hs2[r0 * 32];
        const h8* row1 = (const h8*)&hs2[(r0 + 1) * 32];
#pragma unroll
        for (int j = 0; j < 8; ++j) {
            h8 v0 = row0[j];
            h8 v1 = row1[j];
            acc0 = dot2acc(v0.a, wcol2[4 * j + 0], acc0);
            acc0 = dot2acc(v0.b, wcol2[4 * j + 1], acc0);
            acc0 = dot2acc(v0.c, wcol2[4 * j + 2], acc0);
            acc0 = dot2acc(v0.d, wcol2[4 * j + 3], acc0);
            acc1 = dot2acc(v1.a, wcol2[4 * j + 0], acc1);
            acc1 = dot2acc(v1.b, wcol2[4 * j + 1], acc1);
            acc1 = dot2acc(v1.c, wcol2[4 * j + 2], acc1);
            acc1 = dot2acc(v1.d, wcol2[4 * j + 3], acc1);
        }
        int nbase = grp * 8 + r0;
        out[nbase * 64 + tx]       = __float2half(acc0 * dinv[nbase]);
        out[(nbase + 1) * 64 + tx] = __float2half(acc1 * dinv[nbase + 1]);
    }
}

#define ACC8(v)  { float2 fa = __half22float2((v).a), fb = __half22float2((v).b),  \
                          fc = __half22float2((v).c), fd = __half22float2((v).d);  \
                   a0 += fa.x; a1 += fa.y; a2 += fb.x; a3 += fb.y;                 \
                   a4 += fc.x; a5 += fc.y; a6 += fd.x; a7 += fd.y; }

// ---------------------------------------------------------------- fused gather + relu + next-layer GEMM
// 8 lanes/node (16B h8 gathers), 32 nodes/block, explicit csr index prefetch.
// GEMM phase: lane = output column, W in 32 half2 regs (loaded once per block),
// fdot2 over broadcast fp16 LDS rows -> kills the per-thread W L1 traffic.
__global__ void fused_layer_kernel(const int* __restrict__ row_beg, const int* __restrict__ row_end,
                                   const int* __restrict__ csr_src, const float* __restrict__ dinv,
                                   const __half* __restrict__ xin, const float* __restrict__ b,
                                   const float* __restrict__ Wn, __half* __restrict__ xout) {
    __shared__ alignas(16) __half2 hs16[NB][32];  // 32 rows x 64 fp16 features
    __shared__ float sdinv[NB];
    int tid = threadIdx.x;
    int nl  = tid >> 3;          // local node 0..31
    int l8  = tid & 7;           // feature octet: feats 8*l8 .. 8*l8+7
    int node = blockIdx.x * NB + nl;
    bool valid = node < N_NODES;
    float a0 = 0.f, a1 = 0.f, a2 = 0.f, a3 = 0.f, a4 = 0.f, a5 = 0.f, a6 = 0.f, a7 = 0.f;
    const __half* xbase = xin + 8 * l8;
    if (valid) {
        int beg = row_beg[node];
        int end = row_end[node];
        int e = beg;
        int s0 = 0, s1 = 0, s2 = 0, s3 = 0;
        bool have = (e + 4 <= end);
        if (have) { s0 = csr_src[e]; s1 = csr_src[e + 1]; s2 = csr_src[e + 2]; s3 = csr_src[e + 3]; }
        while (have) {
            int ne = e + 4;
            bool nh = (ne + 4 <= end);
            int t0 = 0, t1 = 0, t2 = 0, t3 = 0;
            if (nh) { t0 = csr_src[ne]; t1 = csr_src[ne + 1]; t2 = csr_src[ne + 2]; t3 = csr_src[ne + 3]; }
            h8 v0 = *(const h8*)(xbase + s0 * 64);
            h8 v1 = *(const h8*)(xbase + s1 * 64);
            h8 v2 = *(const h8*)(xbase + s2 * 64);
            h8 v3 = *(const h8*)(xbase + s3 * 64);
            ACC8(v0); ACC8(v1); ACC8(v2); ACC8(v3);
            s0 = t0; s1 = t1; s2 = t2; s3 = t3;
            e = ne; have = nh;
        }
        for (; e < end; ++e) {
            int s = csr_src[e];
            h8 v = *(const h8*)(xbase + s * 64);
            ACC8(v);
        }
        float d = dinv[node];
        h8 sv = *(const h8*)(xbase + node * 64);
        float2 sa = __half22float2(sv.a), sb2 = __half22float2(sv.b);
        float2 sc = __half22float2(sv.c), sd2 = __half22float2(sv.d);
        const float4 bb0 = *(const float4*)(b + 8 * l8);
        const float4 bb1 = *(const float4*)(b + 8 * l8 + 4);
        float v0 = fmaxf(d * (a0 + sa.x)  + bb0.x, 0.f);
        float v1 = fmaxf(d * (a1 + sa.y)  + bb0.y, 0.f);
        float v2 = fmaxf(d * (a2 + sb2.x) + bb0.z, 0.f);
        float v3 = fmaxf(d * (a3 + sb2.y) + bb0.w, 0.f);
        float v4 = fmaxf(d * (a4 + sc.x)  + bb1.x, 0.f);
        float v5 = fmaxf(d * (a5 + sc.y)  + bb1.y, 0.f);
        float v6 = fmaxf(d * (a6 + sd2.x) + bb1.z, 0.f);
        float v7 = fmaxf(d * (a7 + sd2.y) + bb1.w, 0.f);
        h8 o;
        o.a = __float22half2_rn(make_float2(v0, v1));
        o.b = __float22half2_rn(make_float2(v2, v3));
        o.c = __float22half2_rn(make_float2(v4, v5));
        o.d = __float22half2_rn(make_float2(v6, v7));
        ((h8*)&hs16[nl][0])[l8] = o;
        if (l8 == 0) sdinv[nl] = d;
    }
    __syncthreads();
    // ---- GEMM phase: wave wv handles rows wv*8..wv*8+7, lane tx = output column
    int tx = tid & 63;
    int wv = tid >> 6;
    __half2 wcol2[32];
#pragma unroll
    for (int k2 = 0; k2 < 32; ++k2)
        wcol2[k2] = __floats2half2_rn(Wn[(2 * k2) * 64 + tx], Wn[(2 * k2 + 1) * 64 + tx]);
    int rbase = blockIdx.x * NB;
#pragma unroll
    for (int rr = 0; rr < 8; ++rr) {
        int r = wv * 8 + rr;
        int n2 = rbase + r;
        if (n2 >= N_NODES) break;
        const h8* row = (const h8*)&hs16[r][0];
        float acc = 0.f;
#pragma unroll
        for (int j = 0; j < 8; ++j) {
            h8 v = row[j];
            acc = dot2acc(v.a, wcol2[4 * j + 0], acc);
            acc = dot2acc(v.b, wcol2[4 * j + 1], acc);
            acc = dot2acc(v.c, wcol2[4 * j + 2], acc);
            acc = dot2acc(v.d, wcol2[4 * j + 3], acc);
        }
        xout[n2 * 64 + tx] = __float2half(acc * sdinv[r]);
    }
}

// ---------------------------------------------------------------- fused final gather (no relu) + pooling
__global__ void gather_pool_kernel(const int* __restrict__ row_beg, const int* __restrict__ row_end,
                                   const int* __restrict__ csr_src, const float* __restrict__ dinv,
                                   const __half* __restrict__ xin, const float* __restrict__ b,
                                   const int* __restrict__ batch, float* __restrict__ pool) {
    __shared__ alignas(16) float hsf[NB][64];
    __shared__ int sg[NB];
    __shared__ int allsame;
    int tid = threadIdx.x;
    int nl  = tid >> 3;
    int l8  = tid & 7;
    int node = blockIdx.x * NB + nl;
    bool valid = node < N_NODES;
    float a0 = 0.f, a1 = 0.f, a2 = 0.f, a3 = 0.f, a4 = 0.f, a5 = 0.f, a6 = 0.f, a7 = 0.f;
    const __half* xbase = xin + 8 * l8;
    float v0 = 0.f, v1 = 0.f, v2 = 0.f, v3 = 0.f, v4 = 0.f, v5 = 0.f, v6 = 0.f, v7 = 0.f;
    if (valid) {
        int beg = row_beg[node];
        int end = row_end[node];
        int e = beg;
        int s0 = 0, s1 = 0, s2 = 0, s3 = 0;
        bool have = (e + 4 <= end);
        if (have) { s0 = csr_src[e]; s1 = csr_src[e + 1]; s2 = csr_src[e + 2]; s3 = csr_src[e + 3]; }
        while (have) {
            int ne = e + 4;
            bool nh = (ne + 4 <= end);
            int t0 = 0, t1 = 0, t2 = 0, t3 = 0;
            if (nh) { t0 = csr_src[ne]; t1 = csr_src[ne + 1]; t2 = csr_src[ne + 2]; t3 = csr_src[ne + 3]; }
            h8 w0 = *(const h8*)(xbase + s0 * 64);
            h8 w1 = *(const h8*)(xbase + s1 * 64);
            h8 w2 = *(const h8*)(xbase + s2 * 64);
            h8 w3 = *(const h8*)(xbase + s3 * 64);
            ACC8(w0); ACC8(w1); ACC8(w2); ACC8(w3);
            s0 = t0; s1 = t1; s2 = t2; s3 = t3;
            e = ne; have = nh;
        }
        for (; e < end; ++e) {
            int s = csr_src[e];
            h8 w = *(const h8*)(xbase + s * 64);
            ACC8(w);
        }
        float d = dinv[node];
        h8 sv = *(const h8*)(xbase + node * 64);
        float2 sa = __half22float2(sv.a), sb2 = __half22float2(sv.b);
        float2 sc = __half22float2(sv.c), sd2 = __half22float2(sv.d);
        const float4 bb0 = *(const float4*)(b + 8 * l8);
        const float4 bb1 = *(const float4*)(b + 8 * l8 + 4);
        v0 = d * (a0 + sa.x)  + bb0.x;
        v1 = d * (a1 + sa.y)  + bb0.y;
        v2 = d * (a2 + sb2.x) + bb0.z;
        v3 = d * (a3 + sb2.y) + bb0.w;
        v4 = d * (a4 + sc.x)  + bb1.x;
        v5 = d * (a5 + sc.y)  + bb1.y;
        v6 = d * (a6 + sd2.x) + bb1.z;
        v7 = d * (a7 + sd2.y) + bb1.w;
    }
    if (l8 == 0) sg[nl] = batch[valid ? node : (N_NODES - 1)];
    if (tid == 0) allsame = 1;
    *(float4*)&hsf[nl][8 * l8]     = make_float4(v0, v1, v2, v3);
    *(float4*)&hsf[nl][8 * l8 + 4] = make_float4(v4, v5, v6, v7);
    __syncthreads();
    if (tid < NB && sg[tid] != sg[0]) allsame = 0;   // benign race, all writes = 0
    __syncthreads();
    if (allsame) {
        if (tid < 64) {
            float s = 0.f;
#pragma unroll
            for (int n = 0; n < NB; ++n) s += hsf[n][tid];
            atomicAdd(&pool[sg[0] * 64 + tid], s);
        }
    } else {
        int g = sg[nl];
        atomicAdd(&pool[g * 64 + 8 * l8 + 0], v0);
        atomicAdd(&pool[g * 64 + 8 * l8 + 1], v1);
        atomicAdd(&pool[g * 64 + 8 * l8 + 2], v2);
        atomicAdd(&pool[g * 64 + 8 * l8 + 3], v3);
        atomicAdd(&pool[g * 64 + 8 * l8 + 4], v4);
        atomicAdd(&pool[g * 64 + 8 * l8 + 5], v5);
        atomicAdd(&pool[g * 64 + 8 * l8 + 6], v6);
        atomicAdd(&pool[g * 64 + 8 * l8 + 7], v7);
    }
}

// ---------------------------------------------------------------- head
__global__ void head_kernel(const float* __restrict__ pool, const float* __restrict__ cnt,
                            const float* __restrict__ Wp, const float* __restrict__ bp,
                            float* __restrict__ out) {
    int g = blockIdx.x;
    int k = threadIdx.x;
    float v = pool[g * 64 + k] * Wp[k];
#pragma unroll
    for (int off = 32; off > 0; off >>= 1) v += __shfl_down(v, off);
    if (k == 0) out[g] = v / fmaxf(cnt[g], 1.0f) + bp[0];
}

extern "C" void kernel_launch(void* const* d_in, const int* in_sizes, int n_in,
                              void* d_out, int out_size, void* d_ws, size_t ws_size,
                              hipStream_t stream) {
    const float* x     = (const float*)d_in[0];
    const int*   ei    = (const int*)d_in[1];
    const int*   batch = (const int*)d_in[2];
    const float* W0 = (const float*)d_in[3];
    const float* b0 = (const float*)d_in[4];
    const float* W1 = (const float*)d_in[5];
    const float* b1 = (const float*)d_in[6];
    const float* W2 = (const float*)d_in[7];
    const float* b2 = (const float*)d_in[8];
    const float* Wp = (const float*)d_in[9];
    const float* bp = (const float*)d_in[10];
    float* out = (float*)d_out;

    __half* xws  = (__half*)d_ws;                      // N*64 fp16 (ping)
    __half* xwsB = xws + N_NODES * 64;                 // N*64 fp16 (pong)
    float* dinv    = (float*)(xwsB + N_NODES * 64);    // N
    int*   row_beg = (int*)(dinv + N_NODES);           // N
    int*   row_end = row_beg + N_NODES;                // N
    int*   csr_src = row_end + N_NODES;                // NPART*CAP
    int*   bucket  = csr_src + NPART * CAP;            // NPART*CAP
    int*   pcount  = bucket + NPART * CAP;             // NPART (contiguous with pool+cnt)
    float* pool    = (float*)(pcount + NPART);         // 64*64
    float* cnt     = pool + 64 * 64;                   // 64

    hipMemsetAsync(pcount, 0, (NPART + 64 * 64 + 64) * sizeof(int), stream);

    // ---- CSR build
    bucket_kernel<<<512, 256, 0, stream>>>(ei, pcount, bucket);
    csr_kernel<<<NPART, 256, 0, stream>>>(pcount, bucket, batch, row_beg, row_end, dinv,
                                          csr_src, cnt);

    // ---- layer 0 transform (fp32 input x)
    gemm64_kernel<float><<<1024, 256, 0, stream>>>(x, W0, dinv, xws);
    // ---- fused: layer-0 aggregate + relu + layer-1 transform
    fused_layer_kernel<<<NBLK, 256, 0, stream>>>(row_beg, row_end, csr_src, dinv,
                                                 xws, b0, W1, xwsB);
    // ---- fused: layer-1 aggregate + relu + layer-2 transform
    fused_layer_kernel<<<NBLK, 256, 0, stream>>>(row_beg, row_end, csr_src, dinv,
                                                 xwsB, b1, W2, xws);
    // ---- fused: layer-2 aggregate (no relu) + pooling
    gather_pool_kernel<<<NBLK, 256, 0, stream>>>(row_beg, row_end, csr_src, dinv,
                                                 xws, b2, batch, pool);
    head_kernel<<<64, 64, 0, stream>>>(pool, cnt, Wp, bp, out);
}